// Round 15
// baseline (67.510 us; speedup 1.0000x reference)
//
#include <hip/hip_runtime.h>
#include <math.h>

#define CB 16          // class_bit
#define ALPHA 0.1f
#define LOG2E 1.4426950408889634f
#define LN2F  0.6931471805599453f
#define MAXW 4         // t-tiles per block (grid 25 x 79 = 1975 blocks)
#define N_BS 128       // batch size (fixed by problem)
#define BIT  48        // code length (fixed by problem)

typedef __bf16 bf16x8 __attribute__((ext_vector_type(8)));
typedef float  f32x16 __attribute__((ext_vector_type(16)));
typedef float  f32x2  __attribute__((ext_vector_type(2)));

__device__ __forceinline__ unsigned int f2bf(float x) {
    unsigned int v = __float_as_uint(x);
    return (v + 0x7FFFu + ((v >> 16) & 1u)) >> 16;   // RNE f32->bf16 bits
}
__device__ __forceinline__ f32x2 bfup2(unsigned int p) {
    f32x2 r;
    r.x = __uint_as_float(p << 16);
    r.y = __uint_as_float(p & 0xFFFF0000u);
    return r;
}

// Fused kernel v3:
//  - phase 0 from LDS-staged bf16 u (pitch 25 u32, conflict-free) + bf16 w_D
//    (wave-broadcast reads), f32x2 accumulators -> v_pk_fma_f32
//  - patch slice bf16 pitch-9 (R14, proven) overlapping the staging region:
//    LDS 19,456 B -> 8 blocks/CU capacity
//  - grid 1975 blocks (MAXW=4) to actually FILL that capacity (R14 lesson:
//    occupancy was grid-capped, not LDS-capped)
//  - running-product epilogue (no a[16] array -> -16 VGPR; TLP covers chain)
// Lessons kept: no fences (R6/7), no cross-tile pipelining (R9), minimal
// live state (R10).
__global__ __launch_bounds__(256, 4) void loss_fused(
        const float* __restrict__ u, const float* __restrict__ y,
        const float* __restrict__ w_D,
        const float* __restrict__ U, const float* __restrict__ Yb,
        const int* __restrict__ ind,
        float* __restrict__ partials, float* __restrict__ quant_partials,
        int n_cls, int n_train, int ntile, int GY) {
    __shared__ unsigned int smem[4736];      // 18,944 B (union of regions)
    __shared__ int pflag[MAXW * 32];         //     512 B
    unsigned int* u_st  = smem;              // [128][25] bf16-pair (phase 0)
    unsigned int* wd_st = smem + 3200;       // [4][48][8] bf16-pair (phase 0)
    unsigned int* ubf32 = smem;              // [4][128][9] patch (after sync2)

    const int tid  = threadIdx.x;
    const int lane = tid & 63;
    const int wid  = tid >> 6;
    const int bx   = blockIdx.x;
    const int by   = blockIdx.y;
    const int c    = bx * 4 + wid;           // class for this wave
    const int r    = lane & 31;
    const int h    = lane >> 5;
    const int nw   = (ntile - by + GY - 1) / GY;

    // ---- staging (coalesced float2 reads, packed bf16 writes) ----
    if (tid < MAXW * 32) pflag[tid] = -1;
    #pragma unroll
    for (int it = 0; it < 12; ++it) {                 // u: 3072 u32
        int f = it * 256 + tid;
        int b = f / 24, k2 = f % 24;
        float2 uv = *(const float2*)(u + (size_t)b * BIT + k2 * 2);
        u_st[b * 25 + k2] = f2bf(uv.x) | (f2bf(uv.y) << 16);
    }
    #pragma unroll
    for (int it = 0; it < 6; ++it) {                  // w_D slice: 1536 u32
        int f = it * 256 + tid;
        int cc = f / 384, rest = f % 384;
        float2 wv = *(const float2*)(w_D + (size_t)(bx * 4 + cc) * BIT * CB
                                     + rest * 2);
        wd_st[f] = f2bf(wv.x) | (f2bf(wv.y) << 16);
    }
    __syncthreads();                         // sync1: staging + pflag init

    if (tid < N_BS) {
        int t = ind[tid];
        for (int w = 0; w < nw; ++w) {
            unsigned rl = (unsigned)(t - (by + w * GY) * 32);
            if (rl < 32u) pflag[w * 32 + rl] = tid;   // rows distinct
        }
    }

    // ---- phase 0: accX[j2] = u_[X*32+r][c][h*8 + 2j2, +1] (f32x2) ----
    f32x2 acc0[4] = {}; f32x2 acc1[4] = {};
    f32x2 acc2[4] = {}; f32x2 acc3[4] = {};
    {
        const unsigned int* __restrict__ up0 = u_st + (0 * 32 + r) * 25;
        const unsigned int* __restrict__ up1 = u_st + (1 * 32 + r) * 25;
        const unsigned int* __restrict__ up2 = u_st + (2 * 32 + r) * 25;
        const unsigned int* __restrict__ up3 = u_st + (3 * 32 + r) * 25;
        const unsigned int* __restrict__ wdc = wd_st + wid * 384 + h * 4;
        for (int k2 = 0; k2 < 24; ++k2) {
            unsigned int p0 = up0[k2], p1 = up1[k2];
            unsigned int p2 = up2[k2], p3 = up3[k2];
            #pragma unroll
            for (int kk = 0; kk < 2; ++kk) {
                uint4 wq = *(const uint4*)(wdc + (2 * k2 + kk) * 8);
                f32x2 w0 = bfup2(wq.x), w1 = bfup2(wq.y);
                f32x2 w2 = bfup2(wq.z), w3 = bfup2(wq.w);
                float s0f = kk ? __uint_as_float(p0 & 0xFFFF0000u)
                               : __uint_as_float(p0 << 16);
                float s1f = kk ? __uint_as_float(p1 & 0xFFFF0000u)
                               : __uint_as_float(p1 << 16);
                float s2f = kk ? __uint_as_float(p2 & 0xFFFF0000u)
                               : __uint_as_float(p2 << 16);
                float s3f = kk ? __uint_as_float(p3 & 0xFFFF0000u)
                               : __uint_as_float(p3 << 16);
                f32x2 s0 = {s0f, s0f}, s1 = {s1f, s1f};
                f32x2 s2 = {s2f, s2f}, s3 = {s3f, s3f};
                acc0[0] += s0 * w0; acc0[1] += s0 * w1;
                acc0[2] += s0 * w2; acc0[3] += s0 * w3;
                acc1[0] += s1 * w0; acc1[1] += s1 * w1;
                acc1[2] += s1 * w2; acc1[3] += s1 * w3;
                acc2[0] += s2 * w0; acc2[1] += s2 * w1;
                acc2[2] += s2 * w2; acc2[3] += s2 * w3;
                acc3[0] += s3 * w0; acc3[1] += s3 * w1;
                acc3[2] += s3 * w2; acc3[3] += s3 * w3;
            }
        }
    }

    // ---- quantization partial (each element exactly once: by==0 only) ----
    if (by == 0) {
        float q = 0.f;
        #pragma unroll
        for (int j2 = 0; j2 < 4; ++j2) {
            float vb[8] = {acc0[j2].x, acc0[j2].y, acc1[j2].x, acc1[j2].y,
                           acc2[j2].x, acc2[j2].y, acc3[j2].x, acc3[j2].y};
            #pragma unroll
            for (int i = 0; i < 8; ++i) {
                float v = vb[i];
                float sg = (v > 0.f) ? 1.f : ((v < 0.f) ? -1.f : 0.f);
                float d = v - sg;
                q = fmaf(d, d, q);
            }
        }
        #pragma unroll
        for (int off = 32; off > 0; off >>= 1) q += __shfl_down(q, off, 64);
        if (lane == 0) quant_partials[bx * 4 + wid] = q;
    }

    // ---- vvec/wvec for this class (shfl_xor reduce over the 32-lane half) ----
    float ypc0 = y[(size_t)(0 * 32 + r) * n_cls + c];
    float ypc1 = y[(size_t)(1 * 32 + r) * n_cls + c];
    float ypc2 = y[(size_t)(2 * 32 + r) * n_cls + c];
    float ypc3 = y[(size_t)(3 * 32 + r) * n_cls + c];
    f32x2 y0 = {ypc0, ypc0}, y1 = {ypc1, ypc1};
    f32x2 y2 = {ypc2, ypc2}, y3 = {ypc3, ypc3};
    f32x2 vv[4], ww[4];
    #pragma unroll
    for (int j2 = 0; j2 < 4; ++j2) {
        ww[j2] = acc0[j2] + acc1[j2] + acc2[j2] + acc3[j2];
        vv[j2] = y0 * acc0[j2] + y1 * acc1[j2] + y2 * acc2[j2] + y3 * acc3[j2];
    }
    #pragma unroll
    for (int m = 1; m < 32; m <<= 1) {
        #pragma unroll
        for (int j2 = 0; j2 < 4; ++j2) {
            vv[j2].x += __shfl_xor(vv[j2].x, m, 64);
            vv[j2].y += __shfl_xor(vv[j2].y, m, 64);
            ww[j2].x += __shfl_xor(ww[j2].x, m, 64);
            ww[j2].y += __shfl_xor(ww[j2].y, m, 64);
        }
    }
    float vvf[8], wwf[8];
    #pragma unroll
    for (int j2 = 0; j2 < 4; ++j2) {
        vvf[2 * j2] = vv[j2].x; vvf[2 * j2 + 1] = vv[j2].y;
        wwf[2 * j2] = ww[j2].x; wwf[2 * j2 + 1] = ww[j2].y;
    }

    // ---- B fragments (pre-scaled by log2e) ----
    bf16x8 B0, B1, B2, B3;
    #pragma unroll
    for (int j2 = 0; j2 < 4; ++j2) {
        B0[2 * j2] = (__bf16)(acc0[j2].x * LOG2E);
        B0[2 * j2 + 1] = (__bf16)(acc0[j2].y * LOG2E);
        B1[2 * j2] = (__bf16)(acc1[j2].x * LOG2E);
        B1[2 * j2 + 1] = (__bf16)(acc1[j2].y * LOG2E);
        B2[2 * j2] = (__bf16)(acc2[j2].x * LOG2E);
        B2[2 * j2 + 1] = (__bf16)(acc2[j2].y * LOG2E);
        B3[2 * j2] = (__bf16)(acc3[j2].x * LOG2E);
        B3[2 * j2 + 1] = (__bf16)(acc3[j2].y * LOG2E);
    }

    __syncthreads();                         // sync2: region-A reads done

    // ---- bf16 patch slice (pitch 9 u32: bank-conflict-free) ----
    {
        unsigned int* d0 = &ubf32[(wid * N_BS + 0 * 32 + r) * 9 + h * 4];
        unsigned int* d1 = &ubf32[(wid * N_BS + 1 * 32 + r) * 9 + h * 4];
        unsigned int* d2 = &ubf32[(wid * N_BS + 2 * 32 + r) * 9 + h * 4];
        unsigned int* d3 = &ubf32[(wid * N_BS + 3 * 32 + r) * 9 + h * 4];
        #pragma unroll
        for (int j2 = 0; j2 < 4; ++j2) {
            d0[j2] = f2bf(acc0[j2].x) | (f2bf(acc0[j2].y) << 16);
            d1[j2] = f2bf(acc1[j2].x) | (f2bf(acc1[j2].y) << 16);
            d2[j2] = f2bf(acc2[j2].x) | (f2bf(acc2[j2].y) << 16);
            d3[j2] = f2bf(acc3[j2].x) | (f2bf(acc3[j2].y) << 16);
        }
    }
    __syncthreads();                         // sync3: patch + pflag ready

    // ---- tile loop (zero barriers; R14's proven body) ----
    float acc = 0.f;
    f32x16 zc = {};
    #pragma unroll 1
    for (int w = 0; w < nw; ++w) {
        const int t0  = (by + w * GY) * 32;
        const int row = t0 + r;
        const int rc  = (row < n_train) ? row : (n_train - 1);
        const float* __restrict__ ar = U + ((size_t)rc * n_cls + c) * CB + h * 8;
        float4 a0 = *(const float4*)(ar);
        float4 a1 = *(const float4*)(ar + 4);
        float Yv = Yb[(size_t)rc * n_cls + c];

        const int pf = pflag[w * 32 + r];
        if (pf >= 0) {
            const unsigned int* src = &ubf32[(wid * N_BS + pf) * 9 + h * 4];
            unsigned int w0 = src[0], w1 = src[1], w2 = src[2], w3 = src[3];
            a0.x = __uint_as_float(w0 << 16);
            a0.y = __uint_as_float(w0 & 0xFFFF0000u);
            a0.z = __uint_as_float(w1 << 16);
            a0.w = __uint_as_float(w1 & 0xFFFF0000u);
            a1.x = __uint_as_float(w2 << 16);
            a1.y = __uint_as_float(w2 & 0xFFFF0000u);
            a1.z = __uint_as_float(w3 << 16);
            a1.w = __uint_as_float(w3 & 0xFFFF0000u);
            Yv = y[(size_t)pf * n_cls + c];
        }
        if (row >= n_train) {
            a0 = make_float4(0.f, 0.f, 0.f, 0.f); a1 = a0; Yv = 0.f;
        }

        float sv = a0.x*vvf[0] + a0.y*vvf[1] + a0.z*vvf[2] + a0.w*vvf[3]
                 + a1.x*vvf[4] + a1.y*vvf[5] + a1.z*vvf[6] + a1.w*vvf[7];
        float sw = a0.x*wwf[0] + a0.y*wwf[1] + a0.z*wwf[2] + a0.w*wwf[3]
                 + a1.x*wwf[4] + a1.y*wwf[5] + a1.z*wwf[6] + a1.w*wwf[7];

        bf16x8 A;
        A[0] = (__bf16)a0.x; A[1] = (__bf16)a0.y;
        A[2] = (__bf16)a0.z; A[3] = (__bf16)a0.w;
        A[4] = (__bf16)a1.x; A[5] = (__bf16)a1.y;
        A[6] = (__bf16)a1.z; A[7] = (__bf16)a1.w;

        float accA = 0.f;    // sum |ip'| this tile
        float pp   = 1.f;    // running prod (1 + 2^-|ip'|), 64 factors (1,2]
        #pragma unroll
        for (int bt = 0; bt < 4; ++bt) {
            bf16x8 Bf = (bt == 0) ? B0 : (bt == 1) ? B1 : (bt == 2) ? B2 : B3;
            f32x16 D = __builtin_amdgcn_mfma_f32_32x32x16_bf16(A, Bf, zc,
                                                               0, 0, 0);
            #pragma unroll
            for (int j = 0; j < 16; ++j) {
                float ipa = fabsf(D[j]);
                accA += ipa;
                pp *= (1.0f + __builtin_amdgcn_exp2f(-ipa));
            }
        }
        float accL = __builtin_amdgcn_logf(pp);   // v_log_f32 = log2
        // pad rows contribute exactly LN2F each (pp *= 2), host-corrected
        acc += LN2F * accL + (0.5f * LN2F) * accA + 0.5f * sw - Yv * sv;
    }

    // per-wave reduction only; no block reduce, no final sync
    #pragma unroll
    for (int off = 32; off > 0; off >>= 1)
        acc += __shfl_down(acc, off, 64);
    if (lane == 0) {
        int bid = by * gridDim.x + bx;
        partials[bid * 4 + wid] = acc;
    }
}

__global__ __launch_bounds__(256) void finalize_kernel(
        const float* __restrict__ partials, int nblk,
        const float* __restrict__ quant_partials, int n_quant,
        float* __restrict__ out, double pad_corr,
        double like_scale, double quant_scale) {
    double s = 0.0, q = 0.0;
    for (int i = threadIdx.x; i < nblk; i += 256) s += (double)partials[i];
    for (int i = threadIdx.x; i < n_quant; i += 256) q += (double)quant_partials[i];
    #pragma unroll
    for (int off = 32; off > 0; off >>= 1) {
        s += __shfl_down(s, off, 64);
        q += __shfl_down(q, off, 64);
    }
    __shared__ double dred[4][2];
    int lane = threadIdx.x & 63, wid = threadIdx.x >> 6;
    if (lane == 0) { dred[wid][0] = s; dred[wid][1] = q; }
    __syncthreads();
    if (threadIdx.x == 0) {
        double S = dred[0][0] + dred[1][0] + dred[2][0] + dred[3][0];
        double Q = dred[0][1] + dred[1][1] + dred[2][1] + dred[3][1];
        out[0] = (float)((S - pad_corr) * like_scale + Q * quant_scale);
    }
}

extern "C" void kernel_launch(void* const* d_in, const int* in_sizes, int n_in,
                              void* d_out, int out_size, void* d_ws, size_t ws_size,
                              hipStream_t stream) {
    const float* u   = (const float*)d_in[0];
    const float* y   = (const float*)d_in[1];
    const int*   ind = (const int*)d_in[2];
    const float* U   = (const float*)d_in[3];
    const float* Yb  = (const float*)d_in[4];
    const float* w_D = (const float*)d_in[5];

    const int n_bs    = in_sizes[2];             // 128 (== N_BS)
    const int n_cls   = in_sizes[1] / n_bs;      // 100
    const int n_train = in_sizes[4] / n_cls;     // 10000

    const int totalU = n_bs * n_cls * CB;
    const int ntile  = (n_train + 31) / 32;      // 313
    const int GY     = (ntile + MAXW - 1) / MAXW; // 79
    const int gx     = (n_cls + 3) / 4;          // 25
    const int nblk   = GY * gx;                  // 1975 blocks
    const int npart  = nblk * 4;                 // per-wave partials
    const int nquant = gx * 4;                   // 100 (by==0 column only)

    char* ws = (char*)d_ws;
    size_t off = 0;
    float* partials = (float*)(ws + off);        off += (size_t)npart * 4;
    float* quant_partials = (float*)(ws + off);  off += (size_t)nquant * 4;

    loss_fused<<<dim3(gx, GY), 256, 0, stream>>>(
        u, y, w_D, U, Yb, ind, partials, quant_partials,
        n_cls, n_train, ntile, GY);

    const double ln2 = 0.6931471805599453;
    const double n_pad = (double)((long long)(ntile * 32 - n_train) *
                                  (long long)n_bs * (long long)n_cls);
    const double pad_corr    = ln2 * n_pad;
    const double like_scale  = 1.0 / ((double)n_bs * n_train * n_cls);
    const double quant_scale = (double)ALPHA / (double)totalU;

    finalize_kernel<<<1, 256, 0, stream>>>(partials, npart,
                                           quant_partials, nquant,
                                           (float*)d_out, pad_corr,
                                           like_scale, quant_scale);
}

// Round 16
// 53.242 us; speedup vs baseline: 1.2680x; 1.2680x over previous
//
#include <hip/hip_runtime.h>
#include <math.h>

#define CB 16          // class_bit
#define ALPHA 0.1f
#define LOG2E 1.4426950408889634f
#define LN2F  0.6931471805599453f
#define MAXW 4         // t-tiles per block (grid 25 x 79 = 1975 blocks)
#define N_BS 128       // batch size (fixed by problem)
#define BIT  48        // code length (fixed by problem)

typedef __bf16 bf16x8 __attribute__((ext_vector_type(8)));
typedef float  f32x16 __attribute__((ext_vector_type(16)));

__device__ __forceinline__ unsigned int f2bf(float x) {
    unsigned int v = __float_as_uint(x);
    return (v + 0x7FFFu + ((v >> 16) & 1u)) >> 16;   // RNE f32->bf16 bits
}

// Fused kernel v4: phase 0 on the MFMA pipe.
//  - u_ = u @ w_D via 12 chained mfma_32x32x16_bf16 per wave (A = u rows from
//    global, L1-resident; B = w_D^T bf16 in LDS, cols d>=16 zero)
//  - D (verified layout: col=lane&31, row=(reg&3)+8*(reg>>2)+4*h) scattered
//    as bf16 u16 stores into the slice [cls][b][d] (pitch 18 u16, conflict-ok)
//  - quant from f32 D (by==0 only; d>=16 lanes contribute exactly 0)
//  - main-loop B-frags = raw dword copies of slice rows (pitch-9 dw,
//    stride-9 reads conflict-free); LOG2E scaling moved to A-side (identical)
//  - MAXW=4 grid (1975 blocks) now affordable: phase 0 is ~free
// Lessons kept: no fences (R6/7), no cross-tile pipelining (R9), minimal live
// state (R10), proven tile-loop body (R13), a[8] half-trees (-8 VGPR).
__global__ __launch_bounds__(256, 4) void loss_fused(
        const float* __restrict__ u, const float* __restrict__ y,
        const float* __restrict__ w_D,
        const float* __restrict__ U, const float* __restrict__ Yb,
        const int* __restrict__ ind,
        float* __restrict__ partials, float* __restrict__ quant_partials,
        int n_cls, int n_train, int ntile, int GY) {
    __shared__ unsigned int slice[4 * N_BS * 9];   // 18,432 B bf16 u_ [cls][b][d]
    __shared__ unsigned int wdt[4 * 16 * 25];      //  6,400 B bf16 w_D^T [cls][d][k]
    __shared__ int pflag[MAXW * 32];               //    512 B

    const int tid  = threadIdx.x;
    const int lane = tid & 63;
    const int wid  = tid >> 6;
    const int bx   = blockIdx.x;
    const int by   = blockIdx.y;
    const int c    = bx * 4 + wid;           // class for this wave
    const int r    = lane & 31;
    const int h    = lane >> 5;
    const int nw   = (ntile - by + GY - 1) / GY;

    // ---- staging: w_D slice transposed to bf16 [cls][d][k]; pflag init ----
    if (tid < MAXW * 32) pflag[tid] = -1;
    unsigned short* wdt16w = (unsigned short*)wdt;
    #pragma unroll
    for (int it = 0; it < 12; ++it) {              // 3072 elems, coalesced read
        int f = it * 256 + tid;
        int cc = f / 768, rem = f % 768;           // rem = k*16 + d
        int k = rem >> 4, d = rem & 15;
        float wv = w_D[(size_t)(bx * 4 + cc) * 768 + rem];
        wdt16w[(cc * 16 + d) * 50 + k] = (unsigned short)f2bf(wv);
    }
    __syncthreads();                               // sync1: wdt + pflag init

    if (tid < N_BS) {
        int t = ind[tid];
        #pragma unroll
        for (int w = 0; w < MAXW; ++w) {           // w>=nw: t0 out of range, no-op
            unsigned rl = (unsigned)(t - (by + w * GY) * 32);
            if (rl < 32u) pflag[w * 32 + rl] = tid;
        }
    }

    // ---- phase 0: u_ slice via MFMA (4 bt x 3 chained kt) ----
    unsigned short* sl16 = (unsigned short*)slice;
    const int dcol = lane & 31;
    float qacc = 0.f;
    f32x16 zc = {};
    #pragma unroll 1
    for (int bt = 0; bt < 4; ++bt) {
        const int b0 = bt * 32 + r;
        f32x16 D = zc;
        #pragma unroll
        for (int kt = 0; kt < 3; ++kt) {
            const float* __restrict__ up = u + (size_t)b0 * BIT + kt * 16 + h * 8;
            float4 ua = *(const float4*)(up);
            float4 ub = *(const float4*)(up + 4);
            bf16x8 Af;
            Af[0] = (__bf16)ua.x; Af[1] = (__bf16)ua.y;
            Af[2] = (__bf16)ua.z; Af[3] = (__bf16)ua.w;
            Af[4] = (__bf16)ub.x; Af[5] = (__bf16)ub.y;
            Af[6] = (__bf16)ub.z; Af[7] = (__bf16)ub.w;
            union { unsigned int u32[4]; bf16x8 v; } B;
            B.u32[0] = 0; B.u32[1] = 0; B.u32[2] = 0; B.u32[3] = 0;
            if (r < 16) {       // n = dcol = r (h part only selects k)
                const unsigned int* src = &wdt[(wid * 16 + r) * 25 + kt * 8 + h * 4];
                B.u32[0] = src[0]; B.u32[1] = src[1];
                B.u32[2] = src[2]; B.u32[3] = src[3];
            }
            D = __builtin_amdgcn_mfma_f32_32x32x16_bf16(Af, B.v, D, 0, 0, 0);
        }
        if (by == 0) {          // quant from f32 D; d>=16 lanes hold exact 0
            #pragma unroll
            for (int i = 0; i < 16; ++i) {
                float v = D[i];
                float sg = (v > 0.f) ? 1.f : ((v < 0.f) ? -1.f : 0.f);
                float dd = v - sg;
                qacc = fmaf(dd, dd, qacc);
            }
        }
        if (dcol < 16) {        // scatter bf16 slice: [cls][b][d], pitch 18 u16
            #pragma unroll
            for (int i = 0; i < 16; ++i) {
                int row = (i & 3) + 8 * (i >> 2) + 4 * h;
                sl16[(wid * N_BS + bt * 32 + row) * 18 + dcol] =
                    (unsigned short)f2bf(D[i]);
            }
        }
    }
    if (by == 0) {
        #pragma unroll
        for (int off = 32; off > 0; off >>= 1) qacc += __shfl_down(qacc, off, 64);
        if (lane == 0) quant_partials[bx * 4 + wid] = qacc;
    }

    // ---- vv/ww from own-wave slice (no barrier needed: same-wave data) ----
    float vvf[8], wwf[8];
    {
        const int dd = lane & 15, g = lane >> 4;
        float vv = 0.f, ww = 0.f;
        #pragma unroll 4
        for (int bb = 0; bb < 32; ++bb) {
            int b = g * 32 + bb;
            float uv = __uint_as_float(
                ((unsigned int)sl16[(wid * N_BS + b) * 18 + dd]) << 16);
            ww += uv;
            vv = fmaf(y[(size_t)b * n_cls + c], uv, vv);
        }
        vv += __shfl_xor(vv, 16, 64); vv += __shfl_xor(vv, 32, 64);
        ww += __shfl_xor(ww, 16, 64); ww += __shfl_xor(ww, 32, 64);
        #pragma unroll
        for (int j = 0; j < 8; ++j) {
            vvf[j] = __shfl(vv, h * 8 + j, 64);
            wwf[j] = __shfl(ww, h * 8 + j, 64);
        }
    }

    // ---- main-loop B-frags: raw dword copies (stride-9 -> conflict-free) ----
    bf16x8 BF[4];
    #pragma unroll
    for (int bt = 0; bt < 4; ++bt) {
        const unsigned int* src = &slice[(wid * N_BS + bt * 32 + r) * 9 + h * 4];
        union { unsigned int u32[4]; bf16x8 v; } B;
        B.u32[0] = src[0]; B.u32[1] = src[1];
        B.u32[2] = src[2]; B.u32[3] = src[3];
        BF[bt] = B.v;
    }

    __syncthreads();                               // sync2: pflag ready

    // ---- tile loop (R13's proven body; LOG2E on the A-side) ----
    float acc = 0.f;
    #pragma unroll 1
    for (int w = 0; w < nw; ++w) {
        const int t0  = (by + w * GY) * 32;
        const int row = t0 + r;
        const int rc  = (row < n_train) ? row : (n_train - 1);
        const float* __restrict__ ar = U + ((size_t)rc * n_cls + c) * CB + h * 8;
        float4 a0 = *(const float4*)(ar);
        float4 a1 = *(const float4*)(ar + 4);
        float Yv = Yb[(size_t)rc * n_cls + c];

        const int pf = pflag[w * 32 + r];
        if (pf >= 0) {
            const unsigned int* src = &slice[(wid * N_BS + pf) * 9 + h * 4];
            unsigned int w0 = src[0], w1 = src[1], w2 = src[2], w3 = src[3];
            a0.x = __uint_as_float(w0 << 16);
            a0.y = __uint_as_float(w0 & 0xFFFF0000u);
            a0.z = __uint_as_float(w1 << 16);
            a0.w = __uint_as_float(w1 & 0xFFFF0000u);
            a1.x = __uint_as_float(w2 << 16);
            a1.y = __uint_as_float(w2 & 0xFFFF0000u);
            a1.z = __uint_as_float(w3 << 16);
            a1.w = __uint_as_float(w3 & 0xFFFF0000u);
            Yv = y[(size_t)pf * n_cls + c];
        }
        if (row >= n_train) {
            a0 = make_float4(0.f, 0.f, 0.f, 0.f); a1 = a0; Yv = 0.f;
        }

        float sv = a0.x*vvf[0] + a0.y*vvf[1] + a0.z*vvf[2] + a0.w*vvf[3]
                 + a1.x*vvf[4] + a1.y*vvf[5] + a1.z*vvf[6] + a1.w*vvf[7];
        float sw = a0.x*wwf[0] + a0.y*wwf[1] + a0.z*wwf[2] + a0.w*wwf[3]
                 + a1.x*wwf[4] + a1.y*wwf[5] + a1.z*wwf[6] + a1.w*wwf[7];

        bf16x8 A;                                  // scaled by log2e (was on B)
        A[0] = (__bf16)(a0.x * LOG2E); A[1] = (__bf16)(a0.y * LOG2E);
        A[2] = (__bf16)(a0.z * LOG2E); A[3] = (__bf16)(a0.w * LOG2E);
        A[4] = (__bf16)(a1.x * LOG2E); A[5] = (__bf16)(a1.y * LOG2E);
        A[6] = (__bf16)(a1.z * LOG2E); A[7] = (__bf16)(a1.w * LOG2E);

        float accA = 0.f;    // sum |ip'| this tile
        float pp   = 1.f;    // prod (1 + 2^-|ip'|), 64 factors in (1,2]
        #pragma unroll
        for (int bt = 0; bt < 4; ++bt) {
            f32x16 D = __builtin_amdgcn_mfma_f32_32x32x16_bf16(A, BF[bt], zc,
                                                               0, 0, 0);
            #pragma unroll
            for (int half = 0; half < 2; ++half) {
                float a[8];
                #pragma unroll
                for (int j = 0; j < 8; ++j) {
                    float ipa = fabsf(D[half * 8 + j]);
                    a[j] = 1.0f + __builtin_amdgcn_exp2f(-ipa);
                    accA += ipa;
                }
                a[0] *= a[1]; a[2] *= a[3]; a[4] *= a[5]; a[6] *= a[7];
                a[0] *= a[2]; a[4] *= a[6];
                pp *= a[0] * a[4];
            }
        }
        float accL = __builtin_amdgcn_logf(pp);    // v_log_f32 = log2
        // pad rows contribute exactly LN2F each (pp *= 2), host-corrected
        acc += LN2F * accL + (0.5f * LN2F) * accA + 0.5f * sw - Yv * sv;
    }

    // per-wave reduction only; no block reduce, no final sync
    #pragma unroll
    for (int off = 32; off > 0; off >>= 1)
        acc += __shfl_down(acc, off, 64);
    if (lane == 0) {
        int bid = by * gridDim.x + bx;
        partials[bid * 4 + wid] = acc;
    }
}

__global__ __launch_bounds__(256) void finalize_kernel(
        const float* __restrict__ partials, int nblk,
        const float* __restrict__ quant_partials, int n_quant,
        float* __restrict__ out, double pad_corr,
        double like_scale, double quant_scale) {
    double s = 0.0, q = 0.0;
    for (int i = threadIdx.x; i < nblk; i += 256) s += (double)partials[i];
    for (int i = threadIdx.x; i < n_quant; i += 256) q += (double)quant_partials[i];
    #pragma unroll
    for (int off = 32; off > 0; off >>= 1) {
        s += __shfl_down(s, off, 64);
        q += __shfl_down(q, off, 64);
    }
    __shared__ double dred[4][2];
    int lane = threadIdx.x & 63, wid = threadIdx.x >> 6;
    if (lane == 0) { dred[wid][0] = s; dred[wid][1] = q; }
    __syncthreads();
    if (threadIdx.x == 0) {
        double S = dred[0][0] + dred[1][0] + dred[2][0] + dred[3][0];
        double Q = dred[0][1] + dred[1][1] + dred[2][1] + dred[3][1];
        out[0] = (float)((S - pad_corr) * like_scale + Q * quant_scale);
    }
}

extern "C" void kernel_launch(void* const* d_in, const int* in_sizes, int n_in,
                              void* d_out, int out_size, void* d_ws, size_t ws_size,
                              hipStream_t stream) {
    const float* u   = (const float*)d_in[0];
    const float* y   = (const float*)d_in[1];
    const int*   ind = (const int*)d_in[2];
    const float* U   = (const float*)d_in[3];
    const float* Yb  = (const float*)d_in[4];
    const float* w_D = (const float*)d_in[5];

    const int n_bs    = in_sizes[2];             // 128 (== N_BS)
    const int n_cls   = in_sizes[1] / n_bs;      // 100
    const int n_train = in_sizes[4] / n_cls;     // 10000

    const int totalU = n_bs * n_cls * CB;
    const int ntile  = (n_train + 31) / 32;      // 313
    const int GY     = (ntile + MAXW - 1) / MAXW; // 79
    const int gx     = (n_cls + 3) / 4;          // 25
    const int nblk   = GY * gx;                  // 1975 blocks
    const int npart  = nblk * 4;                 // per-wave partials
    const int nquant = gx * 4;                   // 100 (by==0 column only)

    char* ws = (char*)d_ws;
    size_t off = 0;
    float* partials = (float*)(ws + off);        off += (size_t)npart * 4;
    float* quant_partials = (float*)(ws + off);  off += (size_t)nquant * 4;

    loss_fused<<<dim3(gx, GY), 256, 0, stream>>>(
        u, y, w_D, U, Yb, ind, partials, quant_partials,
        n_cls, n_train, ntile, GY);

    const double ln2 = 0.6931471805599453;
    const double n_pad = (double)((long long)(ntile * 32 - n_train) *
                                  (long long)n_bs * (long long)n_cls);
    const double pad_corr    = ln2 * n_pad;
    const double like_scale  = 1.0 / ((double)n_bs * n_train * n_cls);
    const double quant_scale = (double)ALPHA / (double)totalU;

    finalize_kernel<<<1, 256, 0, stream>>>(partials, npart,
                                           quant_partials, nquant,
                                           (float*)d_out, pad_corr,
                                           like_scale, quant_scale);
}

// Round 17
// 48.782 us; speedup vs baseline: 1.3839x; 1.0914x over previous
//
#include <hip/hip_runtime.h>
#include <math.h>

#define CB 16          // class_bit
#define ALPHA 0.1f
#define LOG2E 1.4426950408889634f
#define LN2F  0.6931471805599453f
#define MAXW 8         // max t-tiles per block
#define N_BS 128       // batch size (fixed by problem)
#define BIT  48        // code length (fixed by problem)
#define UPAD 52        // u row pitch in LDS floats (16B-aligned)

typedef __bf16 bf16x8 __attribute__((ext_vector_type(8)));
typedef float  f32x16 __attribute__((ext_vector_type(16)));

// R13 kernel (best known, 49.4 us) + ONE change: 1-deep register prefetch of
// the next tile's U rows + Yb inside the unroll-1 tile loop (hides the
// ~900-cycle load->use chain under the ~800-cycle epilogue). 9 extra VGPRs,
// no unrolling (R9 lesson), no fences (R6/7), minimal live state (R10).
__global__ __launch_bounds__(256, 4) void loss_fused(
        const float* __restrict__ u, const float* __restrict__ y,
        const float* __restrict__ w_D,
        const float* __restrict__ U, const float* __restrict__ Yb,
        const int* __restrict__ ind,
        float* __restrict__ partials, float* __restrict__ quant_partials,
        int n_cls, int n_train, int ntile, int GY) {
    __shared__ float smf[N_BS * UPAD + 4 * BIT * CB];  // 38,912 B, reused
    __shared__ int pflag[MAXW * 32];                   // 1,024 B
    float* u_lds   = smf;                    // [N_BS][UPAD]      (phase 0)
    float* wd_lds  = smf + N_BS * UPAD;      // [4][BIT][CB]      (phase 0)
    float* u_slice = smf;                    // [4][N_BS][CB]     (after sync2)

    const int tid  = threadIdx.x;
    const int lane = tid & 63;
    const int wid  = tid >> 6;
    const int bx   = blockIdx.x;
    const int by   = blockIdx.y;
    const int c    = bx * 4 + wid;           // class for this wave
    const int r    = lane & 31;
    const int h    = lane >> 5;
    const int nw   = (ntile - by + GY - 1) / GY;

    // ---- stage u + w_D slice into LDS; init pflag ----
    pflag[tid] = -1;                          // MAXW*32 == 256 == blockDim
    #pragma unroll
    for (int it = 0; it < N_BS * (BIT / 4) / 256; ++it) {   // 6 float4 each
        int f = it * 256 + tid;
        int b = f / (BIT / 4), k4 = f % (BIT / 4);
        *(float4*)&u_lds[b * UPAD + k4 * 4] =
            *(const float4*)&u[(size_t)b * BIT + k4 * 4];
    }
    #pragma unroll
    for (int it = 0; it < 4 * BIT * (CB / 4) / 256; ++it) { // 3 float4 each
        int f = it * 256 + tid;
        int cc = f / (BIT * CB / 4), rest = f % (BIT * CB / 4);
        *(float4*)&wd_lds[cc * BIT * CB + rest * 4] =
            *(const float4*)&w_D[(size_t)(bx * 4 + cc) * BIT * CB + rest * 4];
    }
    __syncthreads();                          // sync1: staging + pflag init

    if (tid < N_BS) {
        int t = ind[tid];
        for (int w = 0; w < nw; ++w) {
            unsigned rl = (unsigned)(t - (by + w * GY) * 32);
            if (rl < 32u) pflag[w * 32 + rl] = tid;
        }
    }

    // ---- phase 0: per-lane u_ slice: accX[j] = u_[X*32+r][c][h*8+j] ----
    float acc0[8] = {0,0,0,0,0,0,0,0};
    float acc1[8] = {0,0,0,0,0,0,0,0};
    float acc2[8] = {0,0,0,0,0,0,0,0};
    float acc3[8] = {0,0,0,0,0,0,0,0};
    {
        const float* __restrict__ wdc = wd_lds + wid * BIT * CB + h * 8;
        for (int k4 = 0; k4 < BIT / 4; ++k4) {
            float4 ub0 = *(const float4*)&u_lds[(0 * 32 + r) * UPAD + k4 * 4];
            float4 ub1 = *(const float4*)&u_lds[(1 * 32 + r) * UPAD + k4 * 4];
            float4 ub2 = *(const float4*)&u_lds[(2 * 32 + r) * UPAD + k4 * 4];
            float4 ub3 = *(const float4*)&u_lds[(3 * 32 + r) * UPAD + k4 * 4];
            #pragma unroll
            for (int kk = 0; kk < 4; ++kk) {
                const float* wrow = wdc + (k4 * 4 + kk) * CB;
                float w8[8];
                float4 wa = *(const float4*)(wrow);
                float4 wb = *(const float4*)(wrow + 4);
                w8[0]=wa.x; w8[1]=wa.y; w8[2]=wa.z; w8[3]=wa.w;
                w8[4]=wb.x; w8[5]=wb.y; w8[6]=wb.z; w8[7]=wb.w;
                float s0 = (&ub0.x)[kk], s1 = (&ub1.x)[kk];
                float s2 = (&ub2.x)[kk], s3 = (&ub3.x)[kk];
                #pragma unroll
                for (int j = 0; j < 8; ++j) {
                    acc0[j] = fmaf(s0, w8[j], acc0[j]);
                    acc1[j] = fmaf(s1, w8[j], acc1[j]);
                    acc2[j] = fmaf(s2, w8[j], acc2[j]);
                    acc3[j] = fmaf(s3, w8[j], acc3[j]);
                }
            }
        }
    }

    // ---- quantization partial (each element exactly once: by==0 only) ----
    if (by == 0) {
        float q = 0.f;
        #pragma unroll
        for (int j = 0; j < 8; ++j) {
            float v, sgn, d;
            v = acc0[j]; sgn = (v>0.f)?1.f:((v<0.f)?-1.f:0.f); d = v-sgn; q = fmaf(d,d,q);
            v = acc1[j]; sgn = (v>0.f)?1.f:((v<0.f)?-1.f:0.f); d = v-sgn; q = fmaf(d,d,q);
            v = acc2[j]; sgn = (v>0.f)?1.f:((v<0.f)?-1.f:0.f); d = v-sgn; q = fmaf(d,d,q);
            v = acc3[j]; sgn = (v>0.f)?1.f:((v<0.f)?-1.f:0.f); d = v-sgn; q = fmaf(d,d,q);
        }
        #pragma unroll
        for (int off = 32; off > 0; off >>= 1) q += __shfl_down(q, off, 64);
        if (lane == 0) quant_partials[bx * 4 + wid] = q;
    }

    // ---- vvec/wvec for this class, in registers (shfl_xor reduce) ----
    float ypc0 = y[(size_t)(0 * 32 + r) * n_cls + c];
    float ypc1 = y[(size_t)(1 * 32 + r) * n_cls + c];
    float ypc2 = y[(size_t)(2 * 32 + r) * n_cls + c];
    float ypc3 = y[(size_t)(3 * 32 + r) * n_cls + c];
    float vv[8], ww[8];
    #pragma unroll
    for (int j = 0; j < 8; ++j) {
        ww[j] = acc0[j] + acc1[j] + acc2[j] + acc3[j];
        vv[j] = ypc0*acc0[j] + ypc1*acc1[j] + ypc2*acc2[j] + ypc3*acc3[j];
    }
    #pragma unroll
    for (int m = 1; m < 32; m <<= 1) {
        #pragma unroll
        for (int j = 0; j < 8; ++j) {
            vv[j] += __shfl_xor(vv[j], m, 64);
            ww[j] += __shfl_xor(ww[j], m, 64);
        }
    }

    // ---- B fragments (pre-scaled by log2e) ----
    bf16x8 B0, B1, B2, B3;
    #pragma unroll
    for (int j = 0; j < 8; ++j) {
        B0[j] = (__bf16)(acc0[j] * LOG2E);
        B1[j] = (__bf16)(acc1[j] * LOG2E);
        B2[j] = (__bf16)(acc2[j] * LOG2E);
        B3[j] = (__bf16)(acc3[j] * LOG2E);
    }

    __syncthreads();                          // sync2: all LDS reads done
    // ---- write f32 u_ slice for patch rows (overwrites staging) ----
    {
        float* dst = u_slice + wid * N_BS * CB + r * CB + h * 8;
        *(float4*)(dst + 0*32*CB)     = make_float4(acc0[0],acc0[1],acc0[2],acc0[3]);
        *(float4*)(dst + 0*32*CB + 4) = make_float4(acc0[4],acc0[5],acc0[6],acc0[7]);
        *(float4*)(dst + 1*32*CB)     = make_float4(acc1[0],acc1[1],acc1[2],acc1[3]);
        *(float4*)(dst + 1*32*CB + 4) = make_float4(acc1[4],acc1[5],acc1[6],acc1[7]);
        *(float4*)(dst + 2*32*CB)     = make_float4(acc2[0],acc2[1],acc2[2],acc2[3]);
        *(float4*)(dst + 2*32*CB + 4) = make_float4(acc2[4],acc2[5],acc2[6],acc2[7]);
        *(float4*)(dst + 3*32*CB)     = make_float4(acc3[0],acc3[1],acc3[2],acc3[3]);
        *(float4*)(dst + 3*32*CB + 4) = make_float4(acc3[4],acc3[5],acc3[6],acc3[7]);
    }
    __syncthreads();                          // sync3: u_slice + pflag ready

    // ---- tile loop with 1-deep U/Yb prefetch (zero barriers) ----
    float acc = 0.f;
    f32x16 zc = {};
    // prefetch tile w=0
    int rc0 = by * 32 + r;
    if (rc0 >= n_train) rc0 = n_train - 1;
    const float* __restrict__ ar0 = U + ((size_t)rc0 * n_cls + c) * CB + h * 8;
    float4 a0c = *(const float4*)(ar0);
    float4 a1c = *(const float4*)(ar0 + 4);
    float  Yvc = Yb[(size_t)rc0 * n_cls + c];

    #pragma unroll 1
    for (int w = 0; w < nw; ++w) {
        // issue next tile's loads first (consumed next iteration)
        float4 a0n = a0c, a1n = a1c; float Yvn = Yvc;
        if (w + 1 < nw) {                      // wave-uniform branch
            int rcn = (by + (w + 1) * GY) * 32 + r;
            if (rcn >= n_train) rcn = n_train - 1;
            const float* __restrict__ arn =
                U + ((size_t)rcn * n_cls + c) * CB + h * 8;
            a0n = *(const float4*)(arn);
            a1n = *(const float4*)(arn + 4);
            Yvn = Yb[(size_t)rcn * n_cls + c];
        }

        const int t0  = (by + w * GY) * 32;
        const int row = t0 + r;
        const int pf  = pflag[w * 32 + r];
        if (pf >= 0) {
            const float* src = u_slice + wid * N_BS * CB + pf * CB + h * 8;
            a0c = *(const float4*)(src);
            a1c = *(const float4*)(src + 4);
            Yvc = y[(size_t)pf * n_cls + c];
        }
        if (row >= n_train) {
            a0c = make_float4(0.f, 0.f, 0.f, 0.f); a1c = a0c; Yvc = 0.f;
        }

        // side dots vs in-register vvec/wvec
        float sv = a0c.x*vv[0] + a0c.y*vv[1] + a0c.z*vv[2] + a0c.w*vv[3]
                 + a1c.x*vv[4] + a1c.y*vv[5] + a1c.z*vv[6] + a1c.w*vv[7];
        float sw = a0c.x*ww[0] + a0c.y*ww[1] + a0c.z*ww[2] + a0c.w*ww[3]
                 + a1c.x*ww[4] + a1c.y*ww[5] + a1c.z*ww[6] + a1c.w*ww[7];

        bf16x8 A;
        A[0] = (__bf16)a0c.x; A[1] = (__bf16)a0c.y;
        A[2] = (__bf16)a0c.z; A[3] = (__bf16)a0c.w;
        A[4] = (__bf16)a1c.x; A[5] = (__bf16)a1c.y;
        A[6] = (__bf16)a1c.z; A[7] = (__bf16)a1c.w;

        float accA = 0.f;    // sum |ip'| this tile
        float pp   = 1.f;    // prod (1 + 2^-|ip'|), 64 factors in (1,2]
        #pragma unroll
        for (int bt = 0; bt < 4; ++bt) {
            bf16x8 Bf = (bt == 0) ? B0 : (bt == 1) ? B1 : (bt == 2) ? B2 : B3;
            f32x16 D = __builtin_amdgcn_mfma_f32_32x32x16_bf16(A, Bf, zc,
                                                               0, 0, 0);
            float a[16];
            #pragma unroll
            for (int j = 0; j < 16; ++j) {
                float ipa = fabsf(D[j]);
                a[j] = 1.0f + __builtin_amdgcn_exp2f(-ipa);
                accA += ipa;
            }
            #pragma unroll
            for (int s = 1; s < 16; s <<= 1)
                #pragma unroll
                for (int j = 0; j < 16; j += 2 * s) a[j] *= a[j + s];
            pp *= a[0];
        }
        float accL = __builtin_amdgcn_logf(pp);   // v_log_f32 = log2
        acc += LN2F * accL + (0.5f * LN2F) * accA + 0.5f * sw - Yvc * sv;

        a0c = a0n; a1c = a1n; Yvc = Yvn;          // rotate pipeline
    }

    // per-wave reduction only; no block reduce, no sync
    #pragma unroll
    for (int off = 32; off > 0; off >>= 1)
        acc += __shfl_down(acc, off, 64);
    if (lane == 0) {
        int bid = by * gridDim.x + bx;
        partials[bid * 4 + wid] = acc;
    }
}

__global__ __launch_bounds__(256) void finalize_kernel(
        const float* __restrict__ partials, int nblk,
        const float* __restrict__ quant_partials, int n_quant,
        float* __restrict__ out, double pad_corr,
        double like_scale, double quant_scale) {
    double s = 0.0, q = 0.0;
    for (int i = threadIdx.x; i < nblk; i += 256) s += (double)partials[i];
    for (int i = threadIdx.x; i < n_quant; i += 256) q += (double)quant_partials[i];
    #pragma unroll
    for (int off = 32; off > 0; off >>= 1) {
        s += __shfl_down(s, off, 64);
        q += __shfl_down(q, off, 64);
    }
    __shared__ double dred[4][2];
    int lane = threadIdx.x & 63, wid = threadIdx.x >> 6;
    if (lane == 0) { dred[wid][0] = s; dred[wid][1] = q; }
    __syncthreads();
    if (threadIdx.x == 0) {
        double S = dred[0][0] + dred[1][0] + dred[2][0] + dred[3][0];
        double Q = dred[0][1] + dred[1][1] + dred[2][1] + dred[3][1];
        out[0] = (float)((S - pad_corr) * like_scale + Q * quant_scale);
    }
}

extern "C" void kernel_launch(void* const* d_in, const int* in_sizes, int n_in,
                              void* d_out, int out_size, void* d_ws, size_t ws_size,
                              hipStream_t stream) {
    const float* u   = (const float*)d_in[0];
    const float* y   = (const float*)d_in[1];
    const int*   ind = (const int*)d_in[2];
    const float* U   = (const float*)d_in[3];
    const float* Yb  = (const float*)d_in[4];
    const float* w_D = (const float*)d_in[5];

    const int n_bs    = in_sizes[2];             // 128 (== N_BS)
    const int n_cls   = in_sizes[1] / n_bs;      // 100
    const int n_train = in_sizes[4] / n_cls;     // 10000

    const int totalU = n_bs * n_cls * CB;
    const int ntile  = (n_train + 31) / 32;      // 313
    const int GY     = (ntile + MAXW - 1) / MAXW; // 40
    const int gx     = (n_cls + 3) / 4;          // 25
    const int nblk   = GY * gx;                  // 1000 blocks
    const int npart  = nblk * 4;                 // per-wave partials
    const int nquant = gx * 4;                   // 100 (by==0 column only)

    char* ws = (char*)d_ws;
    size_t off = 0;
    float* partials = (float*)(ws + off);        off += (size_t)npart * 4;
    float* quant_partials = (float*)(ws + off);  off += (size_t)nquant * 4;

    loss_fused<<<dim3(gx, GY), 256, 0, stream>>>(
        u, y, w_D, U, Yb, ind, partials, quant_partials,
        n_cls, n_train, ntile, GY);

    const double ln2 = 0.6931471805599453;
    const double n_pad = (double)((long long)(GY * MAXW * 32 - n_train) *
                                  (long long)n_bs * (long long)n_cls);
    const double pad_corr    = ln2 * n_pad;
    const double like_scale  = 1.0 / ((double)n_bs * n_train * n_cls);
    const double quant_scale = (double)ALPHA / (double)totalU;

    finalize_kernel<<<1, 256, 0, stream>>>(partials, npart,
                                           quant_partials, nquant,
                                           (float*)d_out, pad_corr,
                                           like_scale, quant_scale);
}